// Round 19
// baseline (189.920 us; speedup 1.0000x reference)
//
#include <hip/hip_runtime.h>

// Problem constants (fixed by reference)
#define H    256
#define HE   64
#define NPB  512         // nodes per batch
#define NA   512         // total anchors (8 batches * 64)
#define MU_STEP (20.0f / 63.0f)
#define INV_SIG 3.2f     // 1/0.3125

// ---------------------------------------------------------------------------
__device__ __forceinline__ float wave_sum(float v) {
#pragma unroll
    for (int o = 32; o; o >>= 1) v += __shfl_xor(v, o, 64);
    return v;
}
__device__ __forceinline__ float wave_max(float v) {
#pragma unroll
    for (int o = 32; o; o >>= 1) v = fmaxf(v, __shfl_xor(v, o, 64));
    return v;
}
__device__ __forceinline__ float block_sum1024(float v, float* red16, int t) {
    v = wave_sum(v);
    if ((t & 63) == 0) red16[t >> 6] = v;
    __syncthreads();
    v = 0.f;
#pragma unroll
    for (int i = 0; i < 16; ++i) v += red16[i];
    __syncthreads();
    return v;
}

// ---------------------------------------------------------------------------
// Single kernel: 1 anchor per block, raw weights. 512 blocks x 1024 threads.
// NO min-waves launch hint (r17 lesson: (1024,8) caps VGPR at 32 and spills
// the 16-float flights -> 43 MB scratch writes). Unconstrained, the 1-anchor
// body should land <=64 VGPR -> 8 waves/SIMD -> 2 blocks/CU co-resident:
// each barrier stalls only half the CU's waves. a=(bid&7)*64+(bid>>3) pins
// batch to XCD. Phase C barrier-free with depth-2 prefetch; wave-GEMVs use
// 16-load flights (lane>>4 = output-sub, lane&15 = k-chunk).
// ---------------------------------------------------------------------------
__global__ void __launch_bounds__(1024) fused_all(
    const float* __restrict__ anchor_x, const float* __restrict__ node_x,
    const float* __restrict__ anchor_f, const float* __restrict__ node_f,
    const float* __restrict__ node_mask,
    const float* __restrict__ Wq,  const float* __restrict__ bq,
    const float* __restrict__ Wkv, const float* __restrict__ bkv,
    const float* __restrict__ ln1_g, const float* __restrict__ ln1_b,
    const float* __restrict__ W1, const float* __restrict__ b1,
    const float* __restrict__ W2, const float* __restrict__ b2,
    const float* __restrict__ W3, const float* __restrict__ b3,
    const float* __restrict__ g2,  const float* __restrict__ bb2,
    float* __restrict__ out)
{
    const int bid = blockIdx.x;
    const int b = bid & 7;                   // batch -> XCD
    const int a = b * 64 + (bid >> 3);       // anchor (a>>6 == b)
    const int t  = threadIdx.x;              // 0..1023
    const int wv = t >> 6, l = t & 63;       // wave id (0..15), lane
    const int sub = l >> 4, kc16 = l & 15;   // wave-GEMV: output-sub, k-chunk

    __shared__ __align__(16) float qWe_s[324];   // qW 0-255, qe 256-319
    __shared__ float q_s[256];
    __shared__ float af_s[256];              // anchor_f, later af1
    __shared__ float d10_s[NPB];
    __shared__ float mf_s[NPB];
    __shared__ float lg_s[NPB];
    __shared__ float w_s[NPB];
    __shared__ float snf_s[256], rj_s[64];
    __shared__ float m1_s[512], m2_s[512];
    __shared__ float red[512], red16[16];
    __shared__ int   idx_s[NPB];
    __shared__ int   cnt_s;

    if (t < 256) af_s[t] = anchor_f[(size_t)a * 256 + t];
    if (t == 0) cnt_s = 0;

    // Phase A: d10 + mask factor, one node per thread (t<512)
    if (t < 512) {
        float ax0 = anchor_x[3 * a], ax1 = anchor_x[3 * a + 1], ax2 = anchor_x[3 * a + 2];
        int ng = b * NPB + t;
        float dx = ax0 - node_x[3 * ng]     + 1e-8f;
        float dy = ax1 - node_x[3 * ng + 1] + 1e-8f;
        float dz = ax2 - node_x[3 * ng + 2] + 1e-8f;
        d10_s[t] = sqrtf(dx * dx + dy * dy + dz * dz) * 0.1f;
        mf_s[t]  = (node_mask[ng] - 1.0f) * 1000000.0f;
    }
    __syncthreads();   // af_s, cnt_s, d10_s, mf_s ready

    // ---- Phase B1: q[m] = bq[m] + Wq[m,:].af  (wave-GEMV, 16-load flight) ----
#pragma unroll
    for (int pass = 0; pass < 4; ++pass) {
        int m = pass * 64 + wv * 4 + sub;
        const float* wr = Wq + (size_t)m * 256 + kc16;
        float w16[16];
#pragma unroll
        for (int v = 0; v < 16; ++v) w16[v] = wr[v * 16];
        float acc = 0.f;
#pragma unroll
        for (int v = 0; v < 16; ++v) acc = fmaf(w16[v], af_s[kc16 + v * 16], acc);
#pragma unroll
        for (int o = 8; o >= 1; o >>= 1) acc += __shfl_xor(acc, o, 64);
        if (kc16 == 0) q_s[m] = acc + bq[m];
    }
    __syncthreads();   // q_s ready

    // ---- Phase B2: qW/qe column walk over raw Wkv rows 0..255 (16-batch) ----
    if (t < 320) {
        float acc = 0.f;
        for (int o = 0; o < 256; o += 16) {
            float w16[16];
#pragma unroll
            for (int u = 0; u < 16; ++u) w16[u] = Wkv[(size_t)(o + u) * 320 + t];
#pragma unroll
            for (int u = 0; u < 16; ++u) acc = fmaf(w16[u], q_s[o + u], acc);
        }
        qWe_s[t] = acc;
    }
    // qbk via block reduction (its syncs publish qWe_s)
    const float qbk = block_sum1024((t < 256) ? q_s[t] * bkv[t] : 0.f, red16, t);

    // ---- Phase C: logits, barrier-free, depth-2 prefetch ----
    {
        const float4 qA = ((const float4*)qWe_s)[l];
        const float qeA = qWe_s[256 + l];
        const float muL = l * MU_STEP;
        const float4* nfb = (const float4*)(node_f + (size_t)(b * NPB) * 256);

        float4 f0 = nfb[(size_t)wv * 64 + l];
        float4 f1 = nfb[(size_t)(wv + 16) * 64 + l];
        for (int it = 0; it < 32; ++it) {
            const int n = wv + it * 16;
            float4 fn;
            if (it < 30) fn = nfb[(size_t)(n + 32) * 64 + l];

            float sA = qA.x * f0.x + qA.y * f0.y + qA.z * f0.z + qA.w * f0.w;
            float dA10 = d10_s[n];                       // wave-uniform
            float u = (dA10 - muL) * INV_SIG;
            sA = fmaf(qeA, __expf(-u * u), sA);
#pragma unroll
            for (int o = 1; o < 64; o <<= 1) sA += __shfl_xor(sA, o, 64);
            if (l == 0) lg_s[n] = (sA + qbk) * mf_s[n];
            f0 = f1; f1 = fn;
        }
    }
    __syncthreads();

    // ---- Phase D: softmax over 512 nodes ----
    float lg = (t < 512) ? lg_s[t] : -3.4e38f;
    {
        float m = wave_max(lg);
        if (l == 0) red16[wv] = m;
    }
    __syncthreads();
    float gm = red16[0];
#pragma unroll
    for (int i = 1; i < 16; ++i) gm = fmaxf(gm, red16[i]);
    __syncthreads();
    float e = (t < 512) ? __expf(lg - gm) : 0.f;
    if (t < 512) w_s[t] = e;
    {
        float sm = wave_sum(e);
        if (l == 0) red16[wv] = sm;
    }
    __syncthreads();
    float sm = 0.f;
#pragma unroll
    for (int i = 0; i < 16; ++i) sm += red16[i];
    const float inv = 1.0f / sm;
    if (t < 512 && e > 0.f) { int p = atomicAdd(&cnt_s, 1); idx_s[p] = t; }
    __syncthreads();
    const int cnt = cnt_s;

    // ---- snf (t<256) || rj partials (t>=512), parallel ----
    if (t < 256) {
        float s = 0.f;
        const float* base = node_f + (size_t)(b * NPB) * 256 + t;
        for (int i = 0; i < cnt; ++i) {
            int n = idx_s[i];
            s += w_s[n] * base[(size_t)n * 256];
        }
        snf_s[t] = s;
    } else if (t >= 512) {
        const int tt = t - 512;
        const int j = tt & 63, g = tt >> 6;              // 8 groups x 64 j
        float mu = j * MU_STEP;
        float r = 0.f;
        for (int i = g; i < cnt; i += 8) {
            int n = idx_s[i];
            float uu = (d10_s[n] - mu) * INV_SIG;
            r += w_s[n] * __expf(-uu * uu);
        }
        red[tt] = r;
    }
    __syncthreads();
    if (t < 64) {
        float r = 0.f;
#pragma unroll
        for (int g = 0; g < 8; ++g) r += red[t + 64 * g];
        rj_s[t] = r;
    }
    __syncthreads();

    // ---- upd wave-GEMV over raw Wkv v-rows (16+4 load flight) ----
#pragma unroll
    for (int pass = 0; pass < 4; ++pass) {
        int m = pass * 64 + wv * 4 + sub;
        const float* wr = Wkv + (size_t)(256 + m) * 320 + kc16;
        float w16[16], w4r[4];
#pragma unroll
        for (int v = 0; v < 16; ++v) w16[v] = wr[v * 16];
#pragma unroll
        for (int v = 0; v < 4; ++v) w4r[v] = wr[256 + v * 16];
        float acc = 0.f;
#pragma unroll
        for (int v = 0; v < 16; ++v) acc = fmaf(w16[v], snf_s[kc16 + v * 16], acc);
#pragma unroll
        for (int v = 0; v < 4; ++v) acc = fmaf(w4r[v], rj_s[kc16 + v * 16], acc);
#pragma unroll
        for (int o = 8; o >= 1; o >>= 1) acc += __shfl_xor(acc, o, 64);
        if (kc16 == 0) red[m] = acc;
    }
    __syncthreads();

    // ---- residual + LN1 (t<256) ----
    float x = 0.f;
    if (t < 256) x = af_s[t] + red[t] * inv + bkv[256 + t];
    float mean = block_sum1024(x, red16, t) * (1.0f / 256.0f);
    float xc = (t < 256) ? (x - mean) : 0.f;
    float var = block_sum1024(xc * xc, red16, t) * (1.0f / 256.0f);
    if (t < 256)
        af_s[t] = xc * rsqrtf(var + 1e-5f) * ln1_g[t] + ln1_b[t];   // af1
    __syncthreads();

    // ---- MLP L1 (8 passes, 16-load flight): m1 = relu(W1.af1 + b1) ----
#pragma unroll
    for (int pass = 0; pass < 8; ++pass) {
        int m = pass * 64 + wv * 4 + sub;
        const float* wr = W1 + (size_t)m * 256 + kc16;
        float w16[16];
#pragma unroll
        for (int v = 0; v < 16; ++v) w16[v] = wr[v * 16];
        float acc = 0.f;
#pragma unroll
        for (int v = 0; v < 16; ++v) acc = fmaf(w16[v], af_s[kc16 + v * 16], acc);
#pragma unroll
        for (int o = 8; o >= 1; o >>= 1) acc += __shfl_xor(acc, o, 64);
        if (kc16 == 0) m1_s[m] = fmaxf(acc + b1[m], 0.f);
    }
    __syncthreads();

    // ---- MLP L2 (8 passes, 2x16-load flights): m2 = relu(W2.m1 + b2) ----
#pragma unroll
    for (int pass = 0; pass < 8; ++pass) {
        int m = pass * 64 + wv * 4 + sub;
        const float* wr = W2 + (size_t)m * 512 + kc16;
        float acc = 0.f;
#pragma unroll
        for (int u = 0; u < 32; u += 16) {
            float w16[16];
#pragma unroll
            for (int v = 0; v < 16; ++v) w16[v] = wr[(u + v) * 16];
#pragma unroll
            for (int v = 0; v < 16; ++v)
                acc = fmaf(w16[v], m1_s[kc16 + (u + v) * 16], acc);
        }
#pragma unroll
        for (int o = 8; o >= 1; o >>= 1) acc += __shfl_xor(acc, o, 64);
        if (kc16 == 0) m2_s[m] = fmaxf(acc + b2[m], 0.f);
    }
    __syncthreads();

    // ---- MLP L3 (4 passes, 2x16-load flights): y = W3.m2 + b3 -> red[] ----
#pragma unroll
    for (int pass = 0; pass < 4; ++pass) {
        int m = pass * 64 + wv * 4 + sub;
        const float* wr = W3 + (size_t)m * 512 + kc16;
        float acc = 0.f;
#pragma unroll
        for (int u = 0; u < 32; u += 16) {
            float w16[16];
#pragma unroll
            for (int v = 0; v < 16; ++v) w16[v] = wr[(u + v) * 16];
#pragma unroll
            for (int v = 0; v < 16; ++v)
                acc = fmaf(w16[v], m2_s[kc16 + (u + v) * 16], acc);
        }
#pragma unroll
        for (int o = 8; o >= 1; o >>= 1) acc += __shfl_xor(acc, o, 64);
        if (kc16 == 0) red[m] = acc + b3[m];
    }
    __syncthreads();

    // ---- residual + LN2 -> out (t<256) ----
    float y = 0.f;
    if (t < 256) y = red[t] + af_s[t];
    float mn = block_sum1024(y, red16, t) * (1.0f / 256.0f);
    float yc = (t < 256) ? (y - mn) : 0.f;
    float vr = block_sum1024(yc * yc, red16, t) * (1.0f / 256.0f);
    if (t < 256)
        out[(size_t)a * 256 + t] = yc * rsqrtf(vr + 1e-5f) * g2[t] + bb2[t];
}

// ---------------------------------------------------------------------------
extern "C" void kernel_launch(void* const* d_in, const int* in_sizes, int n_in,
                              void* d_out, int out_size, void* d_ws, size_t ws_size,
                              hipStream_t stream)
{
    const float* anchor_x  = (const float*)d_in[0];
    const float* node_x    = (const float*)d_in[1];
    const float* anchor_f  = (const float*)d_in[2];
    const float* node_f    = (const float*)d_in[3];
    const float* node_mask = (const float*)d_in[6];
    const float* Wq        = (const float*)d_in[7];
    const float* bq        = (const float*)d_in[8];
    const float* Wkv       = (const float*)d_in[9];
    const float* bkv       = (const float*)d_in[10];
    const float* ln1_g     = (const float*)d_in[11];
    const float* ln1_b     = (const float*)d_in[12];
    const float* W1        = (const float*)d_in[13];
    const float* b1        = (const float*)d_in[14];
    const float* W2        = (const float*)d_in[15];
    const float* b2        = (const float*)d_in[16];
    const float* W3        = (const float*)d_in[17];
    const float* b3        = (const float*)d_in[18];
    const float* ln2_g     = (const float*)d_in[19];
    const float* ln2_b     = (const float*)d_in[20];

    fused_all<<<NA, 1024, 0, stream>>>(anchor_x, node_x, anchor_f, node_f,
                                       node_mask, Wq, bq, Wkv, bkv,
                                       ln1_g, ln1_b, W1, b1, W2, b2, W3, b3,
                                       ln2_g, ln2_b, (float*)d_out);
}

// Round 20
// 163.633 us; speedup vs baseline: 1.1606x; 1.1606x over previous
//
#include <hip/hip_runtime.h>

// Problem constants (fixed by reference)
#define H    256
#define HE   64
#define NPB  512         // nodes per batch
#define NA   512         // total anchors (8 batches * 64)
#define MU_STEP (20.0f / 63.0f)
#define INV_SIG 3.2f     // 1/0.3125

// ---------------------------------------------------------------------------
__device__ __forceinline__ float wave_sum(float v) {
#pragma unroll
    for (int o = 32; o; o >>= 1) v += __shfl_xor(v, o, 64);
    return v;
}
__device__ __forceinline__ float wave_max(float v) {
#pragma unroll
    for (int o = 32; o; o >>= 1) v = fmaxf(v, __shfl_xor(v, o, 64));
    return v;
}
__device__ __forceinline__ float block_sum1024(float v, float* red16, int t) {
    v = wave_sum(v);
    if ((t & 63) == 0) red16[t >> 6] = v;
    __syncthreads();
    v = 0.f;
#pragma unroll
    for (int i = 0; i < 16; ++i) v += red16[i];
    __syncthreads();
    return v;
}

// ---------------------------------------------------------------------------
// Single kernel: everything, 2 anchors per block, raw weights.
// 256 blocks x 1024 threads (16 waves/CU, 1 block/CU — verified HW optimum:
// r19 showed two 1024-thread blocks never co-schedule, and 1-anchor blocks
// double weight traffic + barriers). aA=(bid&7)*64+2*(bid>>3), aB=aA+1.
// Phase C barrier-free with depth-2 global prefetch; wave-GEMVs use 16-load
// flights. NOTE (r17): no min-waves hint — (1024,8) caps VGPR at 32 and
// spills the flights to scratch (43 MB writes).
// ---------------------------------------------------------------------------
__global__ void __launch_bounds__(1024) fused_all(
    const float* __restrict__ anchor_x, const float* __restrict__ node_x,
    const float* __restrict__ anchor_f, const float* __restrict__ node_f,
    const float* __restrict__ node_mask,
    const float* __restrict__ Wq,  const float* __restrict__ bq,
    const float* __restrict__ Wkv, const float* __restrict__ bkv,
    const float* __restrict__ ln1_g, const float* __restrict__ ln1_b,
    const float* __restrict__ W1, const float* __restrict__ b1,
    const float* __restrict__ W2, const float* __restrict__ b2,
    const float* __restrict__ W3, const float* __restrict__ b3,
    const float* __restrict__ g2,  const float* __restrict__ bb2,
    float* __restrict__ out)
{
    const int bid = blockIdx.x;
    const int b  = bid & 7;                  // batch -> XCD
    const int pr = bid >> 3;                 // anchor pair 0..31
    const int aA = b * 64 + 2 * pr;
    const int aB = aA + 1;
    const int t  = threadIdx.x;              // 0..1023
    const int wv = t >> 6, l = t & 63;       // wave id (0..15), lane
    const int sub = l >> 4, kc16 = l & 15;   // wave-GEMV: output-sub, k-chunk

    __shared__ __align__(16) float qWe_s[2][324];  // qW 0-255, qe 256-319
    __shared__ float q_s[2][256];
    __shared__ float af_s[2][256];           // anchor_f, later af1
    __shared__ float d10_s[2][NPB];
    __shared__ float mf_s[NPB];
    __shared__ float lg_s[2][NPB];
    __shared__ float w_s[2][NPB];
    __shared__ float snf_s[2][256], rj_s[2][64];
    __shared__ float m1_s[2][512], m2_s[2][512];
    __shared__ float red[512], red16[16];
    __shared__ int   idx_s[2][NPB];
    __shared__ int   cnt_s[2];

    if (t < 256)       af_s[0][t]        = anchor_f[(size_t)aA * 256 + t];
    else if (t < 512)  af_s[1][t - 256]  = anchor_f[(size_t)aB * 256 + (t - 256)];
    if (t < 2) cnt_s[t] = 0;

    // Phase A: d10 for both anchors + mask factor, one node per thread (t<512)
    if (t < 512) {
        float axA0 = anchor_x[3 * aA], axA1 = anchor_x[3 * aA + 1], axA2 = anchor_x[3 * aA + 2];
        float axB0 = anchor_x[3 * aB], axB1 = anchor_x[3 * aB + 1], axB2 = anchor_x[3 * aB + 2];
        int ng = b * NPB + t;
        float nx0 = node_x[3 * ng], nx1 = node_x[3 * ng + 1], nx2 = node_x[3 * ng + 2];
        float dx = axA0 - nx0 + 1e-8f, dy = axA1 - nx1 + 1e-8f, dz = axA2 - nx2 + 1e-8f;
        d10_s[0][t] = sqrtf(dx * dx + dy * dy + dz * dz) * 0.1f;
        dx = axB0 - nx0 + 1e-8f; dy = axB1 - nx1 + 1e-8f; dz = axB2 - nx2 + 1e-8f;
        d10_s[1][t] = sqrtf(dx * dx + dy * dy + dz * dz) * 0.1f;
        mf_s[t] = (node_mask[ng] - 1.0f) * 1000000.0f;
    }
    __syncthreads();   // af_s, cnt_s, d10_s, mf_s ready

    // ---- Phase B1: q[m] = bq[m] + Wq[m,:].af  (wave-GEMV, 16-load flight) ----
#pragma unroll
    for (int pass = 0; pass < 4; ++pass) {
        int m = pass * 64 + wv * 4 + sub;
        const float* wr = Wq + (size_t)m * 256 + kc16;
        float w16[16];
#pragma unroll
        for (int v = 0; v < 16; ++v) w16[v] = wr[v * 16];
        float aAc = 0.f, aBc = 0.f;
#pragma unroll
        for (int v = 0; v < 16; ++v) {
            int c = kc16 + v * 16;
            aAc = fmaf(w16[v], af_s[0][c], aAc);
            aBc = fmaf(w16[v], af_s[1][c], aBc);
        }
#pragma unroll
        for (int o = 8; o >= 1; o >>= 1) {
            aAc += __shfl_xor(aAc, o, 64);
            aBc += __shfl_xor(aBc, o, 64);
        }
        if (kc16 == 0) {
            float bv = bq[m];
            q_s[0][m] = aAc + bv;
            q_s[1][m] = aBc + bv;
        }
    }
    __syncthreads();   // q_s ready

    // ---- Phase B2: qW/qe column walk over raw Wkv rows 0..255 (16-batch) ----
    {
        int ha = -1, col = 0;
        if (t < 320)                   { ha = 0; col = t; }
        else if (t >= 512 && t < 832)  { ha = 1; col = t - 512; }
        if (ha >= 0) {
            const float* qs = q_s[ha];
            float acc = 0.f;
            for (int o = 0; o < 256; o += 16) {
                float w16[16];
#pragma unroll
                for (int u = 0; u < 16; ++u) w16[u] = Wkv[(size_t)(o + u) * 320 + col];
#pragma unroll
                for (int u = 0; u < 16; ++u) acc = fmaf(w16[u], qs[o + u], acc);
            }
            qWe_s[ha][col] = acc;
        }
    }
    // qbk via block reductions (their syncs publish qWe_s)
    float qbkA = block_sum1024((t < 256) ? q_s[0][t] * bkv[t] : 0.f, red16, t);
    float qbkB = block_sum1024((t < 256) ? q_s[1][t] * bkv[t] : 0.f, red16, t);

    // ---- Phase C: logits, barrier-free, depth-2 prefetch ----
    {
        const float4 qA = ((const float4*)qWe_s[0])[l];
        const float4 qB = ((const float4*)qWe_s[1])[l];
        const float qeA = qWe_s[0][256 + l], qeB = qWe_s[1][256 + l];
        const float muL = l * MU_STEP;
        const float4* nfb = (const float4*)(node_f + (size_t)(b * NPB) * 256);

        float4 f0 = nfb[(size_t)wv * 64 + l];
        float4 f1 = nfb[(size_t)(wv + 16) * 64 + l];
        for (int it = 0; it < 32; ++it) {
            const int n = wv + it * 16;
            float4 fn;
            if (it < 30) fn = nfb[(size_t)(n + 32) * 64 + l];

            float sA = qA.x * f0.x + qA.y * f0.y + qA.z * f0.z + qA.w * f0.w;
            float sB = qB.x * f0.x + qB.y * f0.y + qB.z * f0.z + qB.w * f0.w;
            float dA10 = d10_s[0][n], dB10 = d10_s[1][n];   // wave-uniform
            float u = (dA10 - muL) * INV_SIG; sA = fmaf(qeA, __expf(-u * u), sA);
            u = (dB10 - muL) * INV_SIG;       sB = fmaf(qeB, __expf(-u * u), sB);
#pragma unroll
            for (int o = 1; o < 64; o <<= 1) {
                sA += __shfl_xor(sA, o, 64);
                sB += __shfl_xor(sB, o, 64);
            }
            if (l == 0) {
                lg_s[0][n] = (sA + qbkA) * mf_s[n];
                lg_s[1][n] = (sB + qbkB) * mf_s[n];
            }
            f0 = f1; f1 = fn;
        }
    }
    __syncthreads();

    // ---- Phase D: softmax (anchor h8 = t>>9, node n9 = t&511) ----
    const int h8 = t >> 9, n9 = t & 511;
    float lg = lg_s[h8][n9];
    {
        float m = wave_max(lg);
        if (l == 0) red16[wv] = m;
    }
    __syncthreads();
    float gmA = red16[0], gmB = red16[8];
#pragma unroll
    for (int i = 1; i < 8; ++i) { gmA = fmaxf(gmA, red16[i]); gmB = fmaxf(gmB, red16[8 + i]); }
    __syncthreads();
    float e = __expf(lg - (h8 ? gmB : gmA));
    w_s[h8][n9] = e;
    {
        float sm = wave_sum(e);
        if (l == 0) red16[wv] = sm;
    }
    __syncthreads();
    float smA = 0.f, smB = 0.f;
#pragma unroll
    for (int i = 0; i < 8; ++i) { smA += red16[i]; smB += red16[8 + i]; }
    const float invA = 1.0f / smA, invB = 1.0f / smB;
    if (e > 0.f) { int p = atomicAdd(&cnt_s[h8], 1); idx_s[h8][p] = n9; }
    __syncthreads();

    // ---- snf (t<512) || rj partials (t>=512), fully parallel ----
    if (t < 512) {
        const int hh = t >> 8, col = t & 255;
        const int cnt = cnt_s[hh];
        float s = 0.f;
        const float* base = node_f + (size_t)(b * NPB) * 256 + col;
        for (int i = 0; i < cnt; ++i) {
            int n = idx_s[hh][i];
            s += w_s[hh][n] * base[(size_t)n * 256];
        }
        snf_s[hh][col] = s;
    } else {
        const int tt = t - 512;
        const int ha = tt >> 8, j = tt & 63, g = (tt >> 6) & 3;
        const int cnt = cnt_s[ha];
        float mu = j * MU_STEP;
        float r = 0.f;
        for (int i = g; i < cnt; i += 4) {
            int n = idx_s[ha][i];
            float uu = (d10_s[ha][n] - mu) * INV_SIG;
            r += w_s[ha][n] * __expf(-uu * uu);
        }
        red[tt] = r;
    }
    __syncthreads();
    if (t < 128) {
        int ha = t >> 6, j = t & 63;
        rj_s[ha][j] = red[ha * 256 + j] + red[ha * 256 + 64 + j]
                    + red[ha * 256 + 128 + j] + red[ha * 256 + 192 + j];
    }
    __syncthreads();

    // ---- upd wave-GEMV over raw Wkv v-rows (16+4 load flight) ----
#pragma unroll
    for (int pass = 0; pass < 4; ++pass) {
        int m = pass * 64 + wv * 4 + sub;
        const float* wr = Wkv + (size_t)(256 + m) * 320 + kc16;
        float w16[16], w4r[4];
#pragma unroll
        for (int v = 0; v < 16; ++v) w16[v] = wr[v * 16];
#pragma unroll
        for (int v = 0; v < 4; ++v) w4r[v] = wr[256 + v * 16];
        float aAc = 0.f, aBc = 0.f;
#pragma unroll
        for (int v = 0; v < 16; ++v) {
            int c = kc16 + v * 16;
            aAc = fmaf(w16[v], snf_s[0][c], aAc);
            aBc = fmaf(w16[v], snf_s[1][c], aBc);
        }
#pragma unroll
        for (int v = 0; v < 4; ++v) {
            int j = kc16 + v * 16;
            aAc = fmaf(w4r[v], rj_s[0][j], aAc);
            aBc = fmaf(w4r[v], rj_s[1][j], aBc);
        }
#pragma unroll
        for (int o = 8; o >= 1; o >>= 1) {
            aAc += __shfl_xor(aAc, o, 64);
            aBc += __shfl_xor(aBc, o, 64);
        }
        if (kc16 == 0) { red[m] = aAc; red[256 + m] = aBc; }
    }
    __syncthreads();

    // ---- residual + LN1 (t<512: h = t>>8, th = t&255) ----
    const int h = (t >> 8) & 1, th = t & 255;
    float x = 0.f;
    if (t < 512)
        x = af_s[h][th] + red[h * 256 + th] * (h ? invB : invA) + bkv[256 + th];
    {
        float s1 = wave_sum(x);
        if (l == 0) red16[wv] = s1;
    }
    __syncthreads();
    float meanA = (red16[0] + red16[1] + red16[2] + red16[3]) * (1.0f / 256.0f);
    float meanB = (red16[4] + red16[5] + red16[6] + red16[7]) * (1.0f / 256.0f);
    __syncthreads();
    float xc = (t < 512) ? (x - (h ? meanB : meanA)) : 0.f;
    {
        float v1 = wave_sum(xc * xc);
        if (l == 0) red16[wv] = v1;
    }
    __syncthreads();
    float varA = (red16[0] + red16[1] + red16[2] + red16[3]) * (1.0f / 256.0f);
    float varB = (red16[4] + red16[5] + red16[6] + red16[7]) * (1.0f / 256.0f);
    __syncthreads();
    if (t < 512)
        af_s[h][th] = xc * rsqrtf((h ? varB : varA) + 1e-5f) * ln1_g[th] + ln1_b[th];
    __syncthreads();

    // ---- MLP L1 (8 passes, 16-load flight): m1 = relu(W1.af1 + b1) ----
#pragma unroll
    for (int pass = 0; pass < 8; ++pass) {
        int m = pass * 64 + wv * 4 + sub;
        const float* wr = W1 + (size_t)m * 256 + kc16;
        float w16[16];
#pragma unroll
        for (int v = 0; v < 16; ++v) w16[v] = wr[v * 16];
        float aAc = 0.f, aBc = 0.f;
#pragma unroll
        for (int v = 0; v < 16; ++v) {
            int c = kc16 + v * 16;
            aAc = fmaf(w16[v], af_s[0][c], aAc);
            aBc = fmaf(w16[v], af_s[1][c], aBc);
        }
#pragma unroll
        for (int o = 8; o >= 1; o >>= 1) {
            aAc += __shfl_xor(aAc, o, 64);
            aBc += __shfl_xor(aBc, o, 64);
        }
        if (kc16 == 0) {
            float bv = b1[m];
            m1_s[0][m] = fmaxf(aAc + bv, 0.f);
            m1_s[1][m] = fmaxf(aBc + bv, 0.f);
        }
    }
    __syncthreads();

    // ---- MLP L2 (8 passes, 2x16-load flights): m2 = relu(W2.m1 + b2) ----
#pragma unroll
    for (int pass = 0; pass < 8; ++pass) {
        int m = pass * 64 + wv * 4 + sub;
        const float* wr = W2 + (size_t)m * 512 + kc16;
        float aAc = 0.f, aBc = 0.f;
#pragma unroll
        for (int u = 0; u < 32; u += 16) {
            float w16[16];
#pragma unroll
            for (int v = 0; v < 16; ++v) w16[v] = wr[(u + v) * 16];
#pragma unroll
            for (int v = 0; v < 16; ++v) {
                int c = kc16 + (u + v) * 16;
                aAc = fmaf(w16[v], m1_s[0][c], aAc);
                aBc = fmaf(w16[v], m1_s[1][c], aBc);
            }
        }
#pragma unroll
        for (int o = 8; o >= 1; o >>= 1) {
            aAc += __shfl_xor(aAc, o, 64);
            aBc += __shfl_xor(aBc, o, 64);
        }
        if (kc16 == 0) {
            float bv = b2[m];
            m2_s[0][m] = fmaxf(aAc + bv, 0.f);
            m2_s[1][m] = fmaxf(aBc + bv, 0.f);
        }
    }
    __syncthreads();

    // ---- MLP L3 (4 passes, 2x16-load flights): y = W3.m2 + b3 -> red[] ----
#pragma unroll
    for (int pass = 0; pass < 4; ++pass) {
        int m = pass * 64 + wv * 4 + sub;
        const float* wr = W3 + (size_t)m * 512 + kc16;
        float aAc = 0.f, aBc = 0.f;
#pragma unroll
        for (int u = 0; u < 32; u += 16) {
            float w16[16];
#pragma unroll
            for (int v = 0; v < 16; ++v) w16[v] = wr[(u + v) * 16];
#pragma unroll
            for (int v = 0; v < 16; ++v) {
                int c = kc16 + (u + v) * 16;
                aAc = fmaf(w16[v], m2_s[0][c], aAc);
                aBc = fmaf(w16[v], m2_s[1][c], aBc);
            }
        }
#pragma unroll
        for (int o = 8; o >= 1; o >>= 1) {
            aAc += __shfl_xor(aAc, o, 64);
            aBc += __shfl_xor(aBc, o, 64);
        }
        if (kc16 == 0) {
            float bv = b3[m];
            red[m]       = aAc + bv;
            red[256 + m] = aBc + bv;
        }
    }
    __syncthreads();

    // ---- residual + LN2 -> out (t<512: h, th) ----
    float y = 0.f;
    if (t < 512) y = red[h * 256 + th] + af_s[h][th];
    {
        float s1 = wave_sum(y);
        if (l == 0) red16[wv] = s1;
    }
    __syncthreads();
    float mnA = (red16[0] + red16[1] + red16[2] + red16[3]) * (1.0f / 256.0f);
    float mnB = (red16[4] + red16[5] + red16[6] + red16[7]) * (1.0f / 256.0f);
    __syncthreads();
    float yc = (t < 512) ? (y - (h ? mnB : mnA)) : 0.f;
    {
        float v1 = wave_sum(yc * yc);
        if (l == 0) red16[wv] = v1;
    }
    __syncthreads();
    float vrA = (red16[0] + red16[1] + red16[2] + red16[3]) * (1.0f / 256.0f);
    float vrB = (red16[4] + red16[5] + red16[6] + red16[7]) * (1.0f / 256.0f);
    if (t < 512) {
        int aOut = h ? aB : aA;
        out[(size_t)aOut * 256 + th] =
            yc * rsqrtf((h ? vrB : vrA) + 1e-5f) * g2[th] + bb2[th];
    }
}

// ---------------------------------------------------------------------------
extern "C" void kernel_launch(void* const* d_in, const int* in_sizes, int n_in,
                              void* d_out, int out_size, void* d_ws, size_t ws_size,
                              hipStream_t stream)
{
    const float* anchor_x  = (const float*)d_in[0];
    const float* node_x    = (const float*)d_in[1];
    const float* anchor_f  = (const float*)d_in[2];
    const float* node_f    = (const float*)d_in[3];
    const float* node_mask = (const float*)d_in[6];
    const float* Wq        = (const float*)d_in[7];
    const float* bq        = (const float*)d_in[8];
    const float* Wkv       = (const float*)d_in[9];
    const float* bkv       = (const float*)d_in[10];
    const float* ln1_g     = (const float*)d_in[11];
    const float* ln1_b     = (const float*)d_in[12];
    const float* W1        = (const float*)d_in[13];
    const float* b1        = (const float*)d_in[14];
    const float* W2        = (const float*)d_in[15];
    const float* b2        = (const float*)d_in[16];
    const float* W3        = (const float*)d_in[17];
    const float* b3        = (const float*)d_in[18];
    const float* ln2_g     = (const float*)d_in[19];
    const float* ln2_b     = (const float*)d_in[20];

    fused_all<<<256, 1024, 0, stream>>>(anchor_x, node_x, anchor_f, node_f,
                                        node_mask, Wq, bq, Wkv, bkv,
                                        ln1_g, ln1_b, W1, b1, W2, b2, W3, b3,
                                        ln2_g, ln2_b, (float*)d_out);
}